// Round 9
// baseline (511.529 us; speedup 1.0000x reference)
//
#include <hip/hip_runtime.h>
#include <cstdint>
#include <cstddef>

// ---------------- problem constants ----------------
#define D_N     1024
#define K_S     128
#define EDIM    384
#define HID     128
#define NHEAD   4
#define HDIM    32
#define FFD     128
#define NLAYER  2
#define ETOT    (D_N * K_S)
#define NNODES  200000
#define NBINS   (2 * D_N + 2)
#define NCH     1024
#define CHL     (ETOT / NCH)    // 128

// ---------------- workspace layout (bytes) ----------------
#define OFF_ORDER 0u
#define OFF_KEY   0x080000u
#define OFF_SLOT  0x100000u
#define OFF_HIST  0x200000u
#define OFF_TOT   0xA02000u
#define OFF_WBF   0xA08000u
#define OFF_POOL  0xA80000u
#define WP_OFF 0
#define WI_OFF 49152
#define WO_OFF 147456
#define W1_OFF 180224
#define W2_OFF 212992
#define WTOT   245760

typedef __attribute__((ext_vector_type(8))) short  bf16x8;
typedef __attribute__((ext_vector_type(4))) short  short4v;
typedef __attribute__((ext_vector_type(4))) float  f32x4;

__device__ __forceinline__ short f2bf(float f) {
    union { float f; unsigned u; } v; v.f = f;
    unsigned r = v.u + 0x7fffu + ((v.u >> 16) & 1u);
    return (short)(r >> 16);
}
__device__ __forceinline__ int swz_off(int r, int byteInRow, int strideBytes) {
    return (r * strideBytes + byteInRow) ^ ((r & 7) << 4);
}

// ============================================================
// preprocessing (unchanged from round 6)
// ============================================================
__global__ void init_cvt(int* __restrict__ slot, int* __restrict__ hist,
                         const float* __restrict__ p0, const float* __restrict__ p1,
                         const float* __restrict__ p2, const float* __restrict__ p3,
                         const float* __restrict__ p4, short* __restrict__ wbf)
{
    int idx = blockIdx.x * blockDim.x + threadIdx.x;
    int stride = gridDim.x * blockDim.x;
    for (int i = idx; i < NBINS * NCH; i += stride) hist[i] = 0;
    for (int i = idx; i < NNODES; i += stride) slot[i] = D_N;
    int i = idx * 8;
    if (i < WTOT) {
        const float* s;
        if      (i < WI_OFF) s = p0 + i;
        else if (i < WO_OFF) s = p1 + (i - WI_OFF);
        else if (i < W1_OFF) s = p2 + (i - WO_OFF);
        else if (i < W2_OFF) s = p3 + (i - W1_OFF);
        else                 s = p4 + (i - W2_OFF);
        float4 a = *(const float4*)s;
        float4 b = *(const float4*)(s + 4);
        bf16x8 o;
        o[0] = f2bf(a.x); o[1] = f2bf(a.y); o[2] = f2bf(a.z); o[3] = f2bf(a.w);
        o[4] = f2bf(b.x); o[5] = f2bf(b.y); o[6] = f2bf(b.z); o[7] = f2bf(b.w);
        *(bf16x8*)(wbf + i) = o;
    }
}

__global__ void find_neigh(const int* __restrict__ eidx,
                           const int* __restrict__ tgt_idx,
                           int* __restrict__ slot)
{
    __shared__ int wtot[16];
    __shared__ int wbase_s[16];
    __shared__ int neigh[D_N];
    const int tid  = threadIdx.x;          // 1024
    const int lane = tid & 63;
    const int wv   = tid >> 6;
    const int tgt  = tgt_idx[0];
    const int* src = eidx;
    const int* dst = eidx + ETOT;
    const int epc  = ETOT / 1024;
    const int e0   = tid * epc;

    int c = 0;
    const int4* s4 = (const int4*)(src + e0);
    #pragma unroll 8
    for (int i = 0; i < epc / 4; ++i) {
        int4 v = s4[i];
        c += (v.x == tgt) + (v.y == tgt) + (v.z == tgt) + (v.w == tgt);
    }
    int incl = c;
    #pragma unroll
    for (int d = 1; d < 64; d <<= 1) {
        int t = __shfl_up(incl, d, 64);
        if (lane >= d) incl += t;
    }
    if (lane == 63) wtot[wv] = incl;
    __syncthreads();
    if (tid < 16) {
        int s = 0;
        for (int j = 0; j < tid; ++j) s += wtot[j];
        wbase_s[tid] = s;
    }
    __syncthreads();
    int r = wbase_s[wv] + incl - c;
    for (int e = e0; e < e0 + epc; ++e) {
        if (src[e] == tgt) { if (r < D_N) neigh[r] = dst[e]; ++r; }
    }
    __syncthreads();
    int total = wbase_s[15] + wtot[15];
    if (tid < total && tid < D_N) slot[neigh[tid]] = tid;
}

__global__ void compute_key(const int* __restrict__ eidx,
                            const int* __restrict__ tgt_idx,
                            const int* __restrict__ slot,
                            int* __restrict__ key)
{
    int e = blockIdx.x * 256 + threadIdx.x;
    if (e >= ETOT) return;
    int tgt = tgt_idx[0];
    key[e] = slot[eidx[ETOT + e]] * 2 + ((eidx[e] != tgt) ? 1 : 0);
}

__global__ void hist_build(const int* __restrict__ key, int* __restrict__ hist)
{
    const int c = blockIdx.x * 256 + threadIdx.x;
    if (c >= NCH) return;
    const int4* kp = (const int4*)(key + c * CHL);
    int cur = -1, run = 0;
    for (int i = 0; i < CHL / 4; ++i) {
        int4 k4 = kp[i];
        #pragma unroll
        for (int j = 0; j < 4; ++j) {
            int k = (j == 0) ? k4.x : (j == 1) ? k4.y : (j == 2) ? k4.z : k4.w;
            if (k == cur) { ++run; }
            else {
                if (run) hist[cur * NCH + c] += run;
                cur = k; run = 1;
            }
        }
    }
    if (run) hist[cur * NCH + c] += run;
}

__global__ void scan_pass1(const int* __restrict__ hist, int* __restrict__ tot)
{
    int b = blockIdx.x * 256 + threadIdx.x;
    if (b >= NBINS) return;
    const int4* h = (const int4*)(hist + b * NCH);
    int s = 0;
    #pragma unroll 4
    for (int c = 0; c < NCH / 4; ++c) { int4 v = h[c]; s += v.x + v.y + v.z + v.w; }
    tot[b] = s;
}

#define SCN 2176
__global__ void scan_pass2(int* __restrict__ tot)
{
    __shared__ int A[SCN];
    __shared__ int B[SCN];
    const int tid = threadIdx.x;   // 1024
    for (int i = tid; i < SCN; i += 1024) A[i] = (i < NBINS) ? tot[i] : 0;
    __syncthreads();
    int* cur = A; int* nxt = B;
    for (int s = 1; s < SCN; s <<= 1) {
        for (int i = tid; i < SCN; i += 1024) nxt[i] = (i >= s) ? cur[i] + cur[i - s] : cur[i];
        __syncthreads();
        int* t = cur; cur = nxt; nxt = t;
    }
    for (int i = tid; i < NBINS; i += 1024) tot[i] = (i == 0) ? 0 : cur[i - 1];
}

__global__ void scan_pass3(int* __restrict__ hist, const int* __restrict__ base)
{
    const int wvg  = (blockIdx.x * blockDim.x + threadIdx.x) >> 6;
    const int lane = threadIdx.x & 63;
    if (wvg >= NBINS) return;
    int* h = hist + wvg * NCH + lane * 16;
    int4 a0 = ((int4*)h)[0], a1 = ((int4*)h)[1], a2 = ((int4*)h)[2], a3 = ((int4*)h)[3];
    int ls = a0.x + a0.y + a0.z + a0.w + a1.x + a1.y + a1.z + a1.w
           + a2.x + a2.y + a2.z + a2.w + a3.x + a3.y + a3.z + a3.w;
    int incl = ls;
    #pragma unroll
    for (int d = 1; d < 64; d <<= 1) {
        int t = __shfl_up(incl, d, 64);
        if (lane >= d) incl += t;
    }
    int run = base[wvg] + incl - ls;
    int4 o;
    o.x = run; run += a0.x; o.y = run; run += a0.y;
    o.z = run; run += a0.z; o.w = run; run += a0.w; ((int4*)h)[0] = o;
    o.x = run; run += a1.x; o.y = run; run += a1.y;
    o.z = run; run += a1.z; o.w = run; run += a1.w; ((int4*)h)[1] = o;
    o.x = run; run += a2.x; o.y = run; run += a2.y;
    o.z = run; run += a2.z; o.w = run; run += a2.w; ((int4*)h)[2] = o;
    o.x = run; run += a3.x; o.y = run; run += a3.y;
    o.z = run; run += a3.z; o.w = run; run += a3.w; ((int4*)h)[3] = o;
}

__global__ void scatter_order(const int* __restrict__ key,
                              int* __restrict__ hist,
                              int* __restrict__ order)
{
    const int c = blockIdx.x * 256 + threadIdx.x;
    if (c >= NCH) return;
    const int e0 = c * CHL;
    const int4* kp = (const int4*)(key + e0);
    int cur = -1, pos = 0;
    for (int i = 0; i < CHL / 4; ++i) {
        int4 k4 = kp[i];
        #pragma unroll
        for (int j = 0; j < 4; ++j) {
            int k = (j == 0) ? k4.x : (j == 1) ? k4.y : (j == 2) ? k4.z : k4.w;
            if (k != cur) {
                if (cur >= 0) hist[cur * NCH + c] = pos;
                cur = k;
                pos = hist[k * NCH + c];
            }
            if (pos >= 0 && pos < ETOT) order[pos] = e0 + i * 4 + j;
            ++pos;
        }
    }
    if (cur >= 0) hist[cur * NCH + c] = pos;
}

// ============================================================
// MFMA helpers
// ============================================================
template<int CF, int KC, typename GetB>
__device__ __forceinline__ void gemm1(f32x4 (&acc)[CF],
    const char* aB, int aRow0, int aStride, int aColOff, int l15, int g, GetB getB)
{
    #pragma unroll
    for (int kc = 0; kc < KC; ++kc) {
        bf16x8 a = *(const bf16x8*)(aB +
            swz_off(aRow0 + l15, aColOff + kc * 64 + g * 16, aStride));
        #pragma unroll
        for (int cf = 0; cf < CF; ++cf)
            acc[cf] = __builtin_amdgcn_mfma_f32_16x16x32_bf16(a, getB(cf, kc), acc[cf], 0, 0, 0);
    }
}

// stage bf16 matrix rows (contiguous src) into swizzled LDS
template<int ROWB>
__device__ __forceinline__ void stage_w(const char* __restrict__ gsrc, char* ldst,
                                        int nbytes, int tid)
{
    #pragma unroll 4
    for (int u = tid * 16; u < nbytes; u += 512 * 16) {
        int row = u / ROWB;
        int in  = u - row * ROWB;
        *(bf16x8*)(ldst + swz_off(row, in, ROWB)) = *(const bf16x8*)(gsrc + u);
    }
}

// stage with strided source rows (column-slice of a wider matrix)
template<int DROWB, int SROWB>
__device__ __forceinline__ void stage_sl(const char* __restrict__ gsrc, char* ldst,
                                         int nbytes, int tid)
{
    #pragma unroll 4
    for (int u = tid * 16; u < nbytes; u += 512 * 16) {
        int row = u / DROWB;
        int in  = u - row * DROWB;
        *(bf16x8*)(ldst + swz_off(row, in, DROWB)) =
            *(const bf16x8*)(gsrc + (size_t)row * SROWB + in);
    }
}

__device__ __forceinline__ void layer_norm1(f32x4 (&x)[8],
    const float* __restrict__ gg, const float* __restrict__ bb, int l15)
{
    float gv[8], bv[8];
    #pragma unroll
    for (int cf = 0; cf < 8; ++cf) { gv[cf] = gg[l15 + 16 * cf]; bv[cf] = bb[l15 + 16 * cf]; }
    #pragma unroll
    for (int rg = 0; rg < 4; ++rg) {
        float s = 0.f;
        #pragma unroll
        for (int cf = 0; cf < 8; ++cf) s += x[cf][rg];
        s += __shfl_xor(s, 1); s += __shfl_xor(s, 2);
        s += __shfl_xor(s, 4); s += __shfl_xor(s, 8);
        float mean = s * (1.f / 128.f);
        float v = 0.f;
        #pragma unroll
        for (int cf = 0; cf < 8; ++cf) { float d = x[cf][rg] - mean; v += d * d; }
        v += __shfl_xor(v, 1); v += __shfl_xor(v, 2);
        v += __shfl_xor(v, 4); v += __shfl_xor(v, 8);
        float rs = rsqrtf(v * (1.f / 128.f) + 1e-5f);
        #pragma unroll
        for (int cf = 0; cf < 8; ++cf)
            x[cf][rg] = (x[cf][rg] - mean) * rs * gv[cf] + bv[cf];
    }
}

__device__ __forceinline__ void write_hbf(const f32x4 (&x)[8], char* hbf_n,
                                          int l15, int g, int row0)
{
    #pragma unroll
    for (int cf = 0; cf < 8; ++cf)
        #pragma unroll
        for (int rg = 0; rg < 4; ++rg)
            *(short*)(hbf_n + swz_off(row0 + g * 4 + rg, (l15 + 16 * cf) * 2, 256)) =
                f2bf(x[cf][rg]);
}

// ---- attention for one head; accumulates out-proj into hx (WO from L2) ----
__device__ __forceinline__ void attn_one(char* qb, const char* kb, const char* vb,
    const short* __restrict__ WOl, f32x4 (&hx)[8], int hd, int l15, int g, int row0)
{
    // S = Q K^T
    f32x4 sc[8];
    #pragma unroll
    for (int cf = 0; cf < 8; ++cf) sc[cf] = (f32x4){0.f, 0.f, 0.f, 0.f};
    gemm1<8, 1>(sc, qb, row0, 64, 0, l15, g,
        [&](int cf, int kc) {
            (void)kc;
            return *(const bf16x8*)(kb + swz_off(l15 + 16 * cf, g * 16, 64));
        });
    // softmax
    const float SC_ = 0.17677669529663687f;   // 1/sqrt(32)
    float inv_s[4];
    #pragma unroll
    for (int rg = 0; rg < 4; ++rg) {
        float mx = -1e30f;
        #pragma unroll
        for (int cf = 0; cf < 8; ++cf) {
            sc[cf][rg] *= SC_;
            mx = fmaxf(mx, sc[cf][rg]);
        }
        mx = fmaxf(mx, __shfl_xor(mx, 1)); mx = fmaxf(mx, __shfl_xor(mx, 2));
        mx = fmaxf(mx, __shfl_xor(mx, 4)); mx = fmaxf(mx, __shfl_xor(mx, 8));
        float sum = 0.f;
        #pragma unroll
        for (int cf = 0; cf < 8; ++cf) {
            float e = __expf(sc[cf][rg] - mx);
            sc[cf][rg] = e; sum += e;
        }
        sum += __shfl_xor(sum, 1); sum += __shfl_xor(sum, 2);
        sum += __shfl_xor(sum, 4); sum += __shfl_xor(sum, 8);
        inv_s[rg] = 1.f / sum;
    }
    // O = P V via P-chunks overlaying the (consumed, wave-local) q rows
    f32x4 ov[2];
    ov[0] = (f32x4){0.f, 0.f, 0.f, 0.f};
    ov[1] = (f32x4){0.f, 0.f, 0.f, 0.f};
    #pragma unroll
    for (int cc = 0; cc < 4; ++cc) {
        #pragma unroll
        for (int q = 0; q < 2; ++q) {
            int cfi = 2 * cc + q;
            #pragma unroll
            for (int rg = 0; rg < 4; ++rg)
                *(short*)(qb + swz_off(row0 + g * 4 + rg, (l15 + 16 * q) * 2, 64)) =
                    f2bf(sc[cfi][rg] * inv_s[rg]);
        }
        gemm1<2, 1>(ov, qb, row0, 64, 0, l15, g,
            [&](int cf, int kc) {
                (void)kc;
                return *(const bf16x8*)(vb + swz_off(l15 + 16 * cf, cc * 64 + g * 16, 256));
            });
    }
    // O_head -> qb (own rows), out-proj accumulate (B from L2, broadcast)
    #pragma unroll
    for (int cf = 0; cf < 2; ++cf)
        #pragma unroll
        for (int rg = 0; rg < 4; ++rg)
            *(short*)(qb + swz_off(row0 + g * 4 + rg, (l15 + 16 * cf) * 2, 64)) =
                f2bf(ov[cf][rg]);
    gemm1<8, 1>(hx, qb, row0, 64, 0, l15, g,
        [&](int cf, int kc) {
            (void)kc;
            return *(const bf16x8*)(WOl +
                (size_t)(l15 + 16 * cf) * HID + hd * HDIM + g * 8);
        });
}

// ============================================================
// fused transformer: 1 block = 1 neighbor; 512 thr = 8 waves x 16 rows.
// LDS 72 KB -> 2 blocks/CU (16 waves). Demand < 128 VGPR (round-4 profile:
// 116, no spill). Weights staged through a 16K ping-pong buffer; only Wv and
// WO stream from L2. FF = 4 fused quarter-GEMMs with hidden weight staging.
// ============================================================
#define LDS_TOTAL 73728
__global__ __launch_bounds__(512, 2) void fused_mfma(
    const float* __restrict__ edge_attrs,
    const float* __restrict__ ftm,
    const short* __restrict__ wP, const float* __restrict__ projb,
    const short* __restrict__ wI, const float* __restrict__ aib,
    const short* __restrict__ wO, const float* __restrict__ aob,
    const float* __restrict__ l1g, const float* __restrict__ l1b,
    const short* __restrict__ w1, const float* __restrict__ f1b,
    const short* __restrict__ w2, const float* __restrict__ f2b,
    const float* __restrict__ l2g, const float* __restrict__ l2b,
    const int*   __restrict__ order,
    float*       __restrict__ pooled)
{
    __shared__ __align__(16) char sm[LDS_TOTAL];
    char* hbf  = sm;                 // 32 KB [128 tok][256B] swz (wave-local only)
    char* qkv  = sm + 32768;         // 24 KB
    char* q_l  = qkv;                //  8 KB [128][64B]  (wave-local: q / P / O / fbuf)
    char* k_l  = qkv + 8192;         //  8 KB [128][64B]  (cross-wave)
    char* vT   = qkv + 16384;        //  8 KB [32][256B]  (cross-wave)
    char* wb   = sm + 57344;         // 16 KB weight buffer (ping A)
    char* wbB  = qkv + 8192;         // 16 KB ping B (over k_l+vT, FF phase only)
    char* ebuf = qkv;                // 16 KB [128][128B] proj staging
    char* fbuf = q_l;                //  8 KB FF1 output

    const int tid  = threadIdx.x;
    const int w    = tid >> 6;
    const int l    = tid & 63;
    const int l15  = l & 15;
    const int g    = l >> 4;
    const int row0 = 16 * w;
    const int b    = blockIdx.x;

    f32x4 hx[8];

    // ---------------- proj: 6 chunks of 64 in-dims -------------------------
    {
        #pragma unroll
        for (int cf = 0; cf < 8; ++cf) {
            float bs = projb[l15 + 16 * cf];
            hx[cf] = (f32x4){bs, bs, bs, bs};
        }
        const int prow = row0 + (l >> 2);
        const int rowIdx = order[b * K_S + prow];
        const float* arow = edge_attrs + (size_t)rowIdx * EDIM;
        const int doff = (l & 3) * 16;

        for (int ch = 0; ch < 6; ++ch) {
            stage_sl<128, 768>((const char*)wP + ch * 128, wb, 16384, tid);
            #pragma unroll
            for (int j = 0; j < 2; ++j) {
                float4 v0 = *(const float4*)(arow + ch * 64 + doff + j * 8);
                float4 v1 = *(const float4*)(arow + ch * 64 + doff + j * 8 + 4);
                bf16x8 pk;
                pk[0] = f2bf(v0.x); pk[1] = f2bf(v0.y); pk[2] = f2bf(v0.z); pk[3] = f2bf(v0.w);
                pk[4] = f2bf(v1.x); pk[5] = f2bf(v1.y); pk[6] = f2bf(v1.z); pk[7] = f2bf(v1.w);
                *(bf16x8*)(ebuf + swz_off(prow, (doff + j * 8) * 2, 128)) = pk;
            }
            __syncthreads();
            gemm1<8, 2>(hx, ebuf, row0, 128, 0, l15, g,
                [&](int cf, int kc) {
                    return *(const bf16x8*)(wb + swz_off(l15 + 16 * cf, kc * 64 + g * 16, 128));
                });
            __syncthreads();
        }
        if (w == 0 && g == 0) {
            #pragma unroll
            for (int cf = 0; cf < 8; ++cf) hx[cf][0] += ftm[l15 + 16 * cf];
        }
        write_hbf(hx, hbf, l15, g, row0);
        // stage layer-0 head-0 Wq/Wk (wb dead after last chunk barrier)
        stage_w<256>((const char*)wI, wb, 8192, tid);
        stage_w<256>((const char*)(wI + (size_t)HID * HID), wb + 8192, 8192, tid);
        __syncthreads();
    }

    // ---------------- transformer layers ----------------------------------
    for (int ly = 0; ly < NLAYER; ++ly) {
        const short* WIl = wI + (size_t)ly * 3 * HID * HID;
        const float* bI  = aib + ly * 3 * HID;
        const short* WOl = wO + (size_t)ly * HID * HID;
        const float* bO  = aob + ly * HID;
        const short* W1l = w1 + (size_t)ly * FFD * HID;
        const float* b1  = f1b + ly * FFD;
        const short* W2l = w2 + (size_t)ly * HID * FFD;
        const float* b2v = f2b + ly * HID;

        // fold attn-out bias into residual accumulator
        #pragma unroll
        for (int cf = 0; cf < 8; ++cf) {
            float bs = bO[l15 + 16 * cf];
            #pragma unroll
            for (int rg = 0; rg < 4; ++rg) hx[cf][rg] += bs;
        }

        for (int hd = 0; hd < NHEAD; ++hd) {
            // ---- QKV (Wq/Wk from wb, Wv streamed from L2) ----
            f32x4 acc[6];
            #pragma unroll
            for (int cf = 0; cf < 6; ++cf) {
                float bs = bI[(cf >> 1) * HID + hd * HDIM + l15 + 16 * (cf & 1)];
                acc[cf] = (f32x4){bs, bs, bs, bs};
            }
            gemm1<6, 4>(acc, hbf, row0, 256, 0, l15, g,
                [&](int cf, int kc) {
                    if (cf < 2)
                        return *(const bf16x8*)(wb +
                            swz_off(l15 + 16 * cf, kc * 64 + g * 16, 256));
                    else if (cf < 4)
                        return *(const bf16x8*)(wb + 8192 +
                            swz_off(l15 + 16 * (cf - 2), kc * 64 + g * 16, 256));
                    else
                        return *(const bf16x8*)(WIl +
                            (size_t)(2 * HID + hd * HDIM + l15 + 16 * (cf - 4)) * HID +
                            kc * 32 + g * 8);
                });
            #pragma unroll
            for (int cf = 0; cf < 2; ++cf) {
                int dcol = (l15 + 16 * cf) * 2;
                #pragma unroll
                for (int rg = 0; rg < 4; ++rg) {
                    int row = row0 + g * 4 + rg;
                    *(short*)(q_l + swz_off(row, dcol, 64)) = f2bf(acc[cf][rg]);
                    *(short*)(k_l + swz_off(row, dcol, 64)) = f2bf(acc[2 + cf][rg]);
                }
                short4v pv;
                pv[0] = f2bf(acc[4 + cf][0]); pv[1] = f2bf(acc[4 + cf][1]);
                pv[2] = f2bf(acc[4 + cf][2]); pv[3] = f2bf(acc[4 + cf][3]);
                *(short4v*)(vT + swz_off(l15 + 16 * cf, (row0 + g * 4) * 2, 256)) = pv;
            }
            __syncthreads();   // q/k/vT visible; wb free

            // ---- stage next weights (hidden under attention) ----
            if (hd < NHEAD - 1) {
                stage_w<256>((const char*)(WIl + (size_t)((hd + 1) * HDIM) * HID),
                             wb, 8192, tid);
                stage_w<256>((const char*)(WIl + (size_t)(HID + (hd + 1) * HDIM) * HID),
                             wb + 8192, 8192, tid);
            } else {
                stage_w<256>((const char*)W1l, wb, 8192, tid);            // W1 q0
                stage_sl<64, 256>((const char*)W2l, wb + 8192, 8192, tid); // W2 q0
            }
            attn_one(q_l, k_l, vT, WOl, hx, hd, l15, g, row0);
            __syncthreads();   // all QKT done -> k/vT free; staged wb visible
        }

        // ---- LN1 -> hbf (wave-local) ----
        layer_norm1(hx, l1g + ly * HID, l1b + ly * HID, l15);
        write_hbf(hx, hbf, l15, g, row0);

        // ---- FF: 4 fused quarter-GEMMs, ping-pong staged weights ----
        f32x4 yy[8];
        #pragma unroll
        for (int cf = 0; cf < 8; ++cf) {
            float bs = b2v[l15 + 16 * cf];
            yy[cf] = (f32x4){bs, bs, bs, bs};
        }
        #pragma unroll
        for (int qq = 0; qq < 4; ++qq) {
            char* bw = (qq & 1) ? wbB : wb;
            // FF1 quarter: 32 ff-outs
            f32x4 fq[2];
            #pragma unroll
            for (int cf = 0; cf < 2; ++cf) {
                float bs = b1[qq * 32 + l15 + 16 * cf];
                fq[cf] = (f32x4){bs, bs, bs, bs};
            }
            gemm1<2, 4>(fq, hbf, row0, 256, 0, l15, g,
                [&](int cf, int kc) {
                    return *(const bf16x8*)(bw + swz_off(l15 + 16 * cf, kc * 64 + g * 16, 256));
                });
            // stage next quarter (target = buffer not read this quarter)
            if (qq < 3) {
                char* nb = (qq & 1) ? wb : wbB;
                stage_w<256>((const char*)(W1l + (size_t)((qq + 1) * 32) * HID),
                             nb, 8192, tid);
                stage_sl<64, 256>((const char*)W2l + (qq + 1) * 64, nb + 8192, 8192, tid);
            } else if (ly + 1 < NLAYER) {
                const short* WIn = wI + (size_t)(ly + 1) * 3 * HID * HID;
                stage_w<256>((const char*)WIn, wb, 8192, tid);
                stage_w<256>((const char*)(WIn + (size_t)HID * HID), wb + 8192, 8192, tid);
            }
            // relu -> fbuf (own rows)
            #pragma unroll
            for (int cf = 0; cf < 2; ++cf)
                #pragma unroll
                for (int rg = 0; rg < 4; ++rg)
                    *(short*)(fbuf + swz_off(row0 + g * 4 + rg, (l15 + 16 * cf) * 2, 64)) =
                        f2bf(fmaxf(fq[cf][rg], 0.f));
            // FF2 quarter accumulate
            gemm1<8, 1>(yy, fbuf, row0, 64, 0, l15, g,
                [&](int cf, int kc) {
                    (void)kc;
                    return *(const bf16x8*)(bw + 8192 + swz_off(l15 + 16 * cf, g * 16, 64));
                });
            __syncthreads();
        }
        #pragma unroll
        for (int cf = 0; cf < 8; ++cf) yy[cf] += hx[cf];
        layer_norm1(yy, l2g + ly * HID, l2b + ly * HID, l15);
        #pragma unroll
        for (int cf = 0; cf < 8; ++cf) hx[cf] = yy[cf];
        write_hbf(hx, hbf, l15, g, row0);
    } // layers

    // ---------------- pool over the 128 tokens -----------------------------
    float* pool_s = (float*)qkv;
    #pragma unroll
    for (int cf = 0; cf < 8; ++cf) {
        float s = hx[cf][0] + hx[cf][1] + hx[cf][2] + hx[cf][3];
        s += __shfl_xor(s, 16); s += __shfl_xor(s, 32);
        if (g == 0) pool_s[w * 128 + l15 + 16 * cf] = s;
    }
    __syncthreads();
    if (tid < 128) {
        float s = 0.f;
        #pragma unroll
        for (int ww = 0; ww < 8; ++ww) s += pool_s[ww * 128 + tid];
        pooled[b * HID + tid] = s * (1.f / 128.f);
    }
}

// ============================================================
// final mean over neighbors + prediction head
// ============================================================
__global__ void final_pred(const float* __restrict__ pooled,
                           const float* __restrict__ w1, const float* __restrict__ b1,
                           const float* __restrict__ w2, const float* __restrict__ b2,
                           float* __restrict__ out)
{
    __shared__ float part[4][HID];
    __shared__ float fin[HID];
    __shared__ float hm[HID];
    const int tid = threadIdx.x;           // 512
    const int f = tid & 127, q = tid >> 7;
    float s = 0.f;
    for (int bb = q * 256; bb < (q + 1) * 256; ++bb) s += pooled[bb * HID + f];
    part[q][f] = s;
    __syncthreads();
    if (tid < HID) {
        fin[tid] = (part[0][tid] + part[1][tid] + part[2][tid] + part[3][tid])
                   * (1.f / (float)D_N);
    }
    __syncthreads();
    if (tid < HID) {
        float a = b1[tid];
        for (int k = 0; k < HID; ++k) a += fin[k] * w1[tid * HID + k];
        hm[tid] = fmaxf(a, 0.f) * w2[tid];
    }
    __syncthreads();
    if (tid == 0) {
        float z = 0.f;
        for (int j = 0; j < HID; ++j) z += hm[j];
        z += b2[0];
        out[0] = 1.f / (1.f + __expf(-z));
    }
}

// ============================================================
// launch
// ============================================================
extern "C" void kernel_launch(void* const* d_in, const int* in_sizes, int n_in,
                              void* d_out, int out_size, void* d_ws, size_t ws_size,
                              hipStream_t stream)
{
    (void)in_sizes; (void)n_in; (void)out_size; (void)ws_size;

    const int*   tgt   = (const int*)  d_in[0];
    const int*   eidx  = (const int*)  d_in[2];
    const float* eattr = (const float*)d_in[3];
    const float* ftm   = (const float*)d_in[4];
    const float* projw = (const float*)d_in[5];
    const float* projb = (const float*)d_in[6];
    const float* aiw   = (const float*)d_in[7];
    const float* aib   = (const float*)d_in[8];
    const float* aow   = (const float*)d_in[9];
    const float* aob   = (const float*)d_in[10];
    const float* l1g   = (const float*)d_in[11];
    const float* l1b   = (const float*)d_in[12];
    const float* f1w   = (const float*)d_in[13];
    const float* f1b   = (const float*)d_in[14];
    const float* f2w   = (const float*)d_in[15];
    const float* f2b   = (const float*)d_in[16];
    const float* l2g   = (const float*)d_in[17];
    const float* l2b   = (const float*)d_in[18];
    const float* pw1   = (const float*)d_in[19];
    const float* pb1   = (const float*)d_in[20];
    const float* pw2   = (const float*)d_in[21];
    const float* pb2   = (const float*)d_in[22];

    char* ws = (char*)d_ws;
    int*   order  = (int*)  (ws + OFF_ORDER);
    int*   key    = (int*)  (ws + OFF_KEY);
    int*   slot   = (int*)  (ws + OFF_SLOT);
    int*   hist   = (int*)  (ws + OFF_HIST);
    int*   tot    = (int*)  (ws + OFF_TOT);
    float* pooled = (float*)(ws + OFF_POOL);
    short* wbf    = (short*)(ws + OFF_WBF);

    init_cvt     <<<dim3(2048), dim3(256),  0, stream>>>(slot, hist,
                                                         projw, aiw, aow, f1w, f2w, wbf);
    find_neigh   <<<dim3(1),    dim3(1024), 0, stream>>>(eidx, tgt, slot);
    compute_key  <<<dim3(512),  dim3(256),  0, stream>>>(eidx, tgt, slot, key);
    hist_build   <<<dim3(4),    dim3(256),  0, stream>>>(key, hist);
    scan_pass1   <<<dim3(9),    dim3(256),  0, stream>>>(hist, tot);
    scan_pass2   <<<dim3(1),    dim3(1024), 0, stream>>>(tot);
    scan_pass3   <<<dim3(513),  dim3(256),  0, stream>>>(hist, tot);
    scatter_order<<<dim3(4),    dim3(256),  0, stream>>>(key, hist, order);

    fused_mfma<<<dim3(D_N), dim3(512), 0, stream>>>(
        eattr, ftm,
        wbf + WP_OFF, projb,
        wbf + WI_OFF, aib,
        wbf + WO_OFF, aob,
        l1g, l1b,
        wbf + W1_OFF, f1b,
        wbf + W2_OFF, f2b,
        l2g, l2b,
        order, pooled);

    final_pred<<<dim3(1), dim3(512), 0, stream>>>(pooled, pw1, pb1, pw2, pb2, (float*)d_out);
}